// Round 1
// baseline (19948.737 us; speedup 1.0000x reference)
//
#include <hip/hip_runtime.h>
#include <cstdint>
#include <cstddef>

// PCD Align (EDVR) — full pipeline in fp32.
// B=4, NF=64, DG=8, K=9. Levels: L3 32x32, L2 64x64, L1 128x128.

// ---------------------------------------------------------------- conv 3x3
// One block = 16x16 spatial tile, all OC output channels accumulated in VGPRs.
// Input may be a virtual concat of in1 (C1 ch) and in2 (C2 ch, scaled by scale2).
// Weights Wg laid out [OC_total][C][3][3]; chunking over output channels via
// blockIdx.z = b*nChunk + chunk (used for the 216-channel offset-mask conv).
template<int C1, int C2, int OC, bool RELU>
__global__ __launch_bounds__(256)
void conv3x3_k(const float* __restrict__ in1, const float* __restrict__ in2,
               float scale2,
               const float* __restrict__ Wg, const float* __restrict__ bg,
               float* __restrict__ out, int H, int W, int ocStride, int nChunk)
{
    constexpr int C = C1 + C2;
    const int b     = blockIdx.z / nChunk;
    const int chunk = blockIdx.z % nChunk;
    const float* Wc = Wg + (size_t)chunk * OC * C * 9;
    const float* bc = bg + chunk * OC;
    const int o0 = chunk * OC;
    const int tx = threadIdx.x, ty = threadIdx.y;
    const int tid = ty * 16 + tx;
    const int h0 = blockIdx.y * 16, w0 = blockIdx.x * 16;
    const size_t HW = (size_t)H * W;

    __shared__ float tile[4][18][19];   // +1 pad on fastest dim

    float acc[OC];
#pragma unroll
    for (int o = 0; o < OC; ++o) acc[o] = 0.f;

    for (int c0 = 0; c0 < C; c0 += 4) {
        __syncthreads();
        // stage 4 channels of the 18x18 halo tile
        for (int i = tid; i < 4 * 18 * 18; i += 256) {
            int cc = i / 324;
            int r  = i - cc * 324;
            int y  = r / 18, x = r - y * 18;
            int gy = h0 + y - 1, gx = w0 + x - 1;
            int c  = c0 + cc;
            float v = 0.f;
            if (gy >= 0 && gy < H && gx >= 0 && gx < W) {
                if (C2 == 0 || c < C1) {
                    v = in1[((size_t)b * C1 + c) * HW + (size_t)gy * W + gx];
                } else {
                    v = in2[((size_t)b * C2 + (c - C1)) * HW + (size_t)gy * W + gx] * scale2;
                }
            }
            tile[cc][y][x] = v;
        }
        __syncthreads();

        for (int cc = 0; cc < 4; ++cc) {
            float v[9];
#pragma unroll
            for (int dy = 0; dy < 3; ++dy)
#pragma unroll
                for (int dx = 0; dx < 3; ++dx)
                    v[dy * 3 + dx] = tile[cc][ty + dy][tx + dx];
            const float* wp = Wc + (size_t)(c0 + cc) * 9;
#pragma unroll
            for (int o = 0; o < OC; ++o) {   // full unroll: acc[] must stay in VGPRs
                float a = acc[o];
#pragma unroll
                for (int k = 0; k < 9; ++k)
                    a = fmaf(wp[(size_t)o * C * 9 + k], v[k], a);
                acc[o] = a;
            }
        }
    }

    const int h = h0 + ty, w = w0 + tx;
    float* op = out + ((size_t)b * ocStride + o0) * HW + (size_t)h * W + w;
#pragma unroll
    for (int o = 0; o < OC; ++o) {
        float r = acc[o] + bc[o];
        if (RELU) r = (r >= 0.f) ? r : 0.1f * r;
        op[(size_t)o * HW] = r;
    }
}

// ------------------------------------------------- dcn_w transpose  [o][c][k] -> [k][c][o]
__global__ void transpose_dcnw(const float* __restrict__ w, float* __restrict__ wt)
{
    int i = blockIdx.x * 256 + threadIdx.x;
    if (i >= 64 * 64 * 9) return;
    int o = i / 576;
    int r = i - o * 576;
    int c = r / 9;
    int k = r - c * 9;
    wt[((size_t)k * 64 + c) * 64 + o] = w[i];
}

// ---------------------------------------------------------------- DCNv2
// x: [B,64,H,W]; om: [B,216,H,W] raw conv output (o1|o2|m);
// Wt: [9][64][64] (k,c,o); out: [B,64,H,W].
template<bool RELU>
__global__ __launch_bounds__(256)
void dcn_k(const float* __restrict__ x, const float* __restrict__ om,
           const float* __restrict__ Wt, const float* __restrict__ bg,
           float* __restrict__ out, int H, int W)
{
    const int b = blockIdx.z;
    const int tx = threadIdx.x, ty = threadIdx.y;
    const int h = blockIdx.y * 16 + ty, w = blockIdx.x * 16 + tx;
    const size_t HW = (size_t)H * W;

    float acc[64];
#pragma unroll
    for (int o = 0; o < 64; ++o) acc[o] = 0.f;

    const float* omb = om + (size_t)b * 216 * HW + (size_t)h * W + w;
    const float* xb  = x + (size_t)b * 64 * HW;

    for (int g = 0; g < 8; ++g) {
        for (int k = 0; k < 9; ++k) {
            const int ch = g * 9 + k;
            float oy = omb[(size_t)ch * HW];
            float ox = omb[(size_t)(72 + ch) * HW];
            float mr = omb[(size_t)(144 + ch) * HW];
            float m  = 1.f / (1.f + expf(-mr));

            float py = oy + (float)(k / 3 - 1) + (float)h;
            float px = ox + (float)(k % 3 - 1) + (float)w;
            float fy = floorf(py), fx = floorf(px);
            float wy = py - fy, wx = px - fx;
            int y0 = (int)fy, x0 = (int)fx;
            int y1 = y0 + 1, x1 = x0 + 1;
            bool vy0 = (y0 >= 0) & (y0 < H), vy1 = (y1 >= 0) & (y1 < H);
            bool vx0 = (x0 >= 0) & (x0 < W), vx1 = (x1 >= 0) & (x1 < W);
            int y0c = y0 < 0 ? 0 : (y0 >= H ? H - 1 : y0);
            int y1c = y1 < 0 ? 0 : (y1 >= H ? H - 1 : y1);
            int x0c = x0 < 0 ? 0 : (x0 >= W ? W - 1 : x0);
            int x1c = x1 < 0 ? 0 : (x1 >= W ? W - 1 : x1);
            // fold mask + per-corner zero-pad validity into bilinear weights
            float w00 = (1.f - wy) * (1.f - wx) * m * ((vy0 & vx0) ? 1.f : 0.f);
            float w01 = (1.f - wy) * wx         * m * ((vy0 & vx1) ? 1.f : 0.f);
            float w10 = wy         * (1.f - wx) * m * ((vy1 & vx0) ? 1.f : 0.f);
            float w11 = wy         * wx         * m * ((vy1 & vx1) ? 1.f : 0.f);
            size_t i00 = (size_t)y0c * W + x0c, i01 = (size_t)y0c * W + x1c;
            size_t i10 = (size_t)y1c * W + x0c, i11 = (size_t)y1c * W + x1c;

            float s[8];
#pragma unroll
            for (int cg = 0; cg < 8; ++cg) {
                const float* xc = xb + (size_t)(g * 8 + cg) * HW;
                s[cg] = w00 * xc[i00] + w01 * xc[i01] + w10 * xc[i10] + w11 * xc[i11];
            }
            const float* wk = Wt + ((size_t)k * 64 + g * 8) * 64;
#pragma unroll
            for (int cg = 0; cg < 8; ++cg) {
                float sv = s[cg];
                const float* wko = wk + cg * 64;
#pragma unroll
                for (int o = 0; o < 64; ++o)
                    acc[o] = fmaf(wko[o], sv, acc[o]);
            }
        }
    }

    float* op = out + ((size_t)b * 64) * HW + (size_t)h * W + w;
#pragma unroll
    for (int o = 0; o < 64; ++o) {
        float r = acc[o] + bg[o];
        if (RELU) r = (r >= 0.f) ? r : 0.1f * r;
        op[(size_t)o * HW] = r;
    }
}

// ------------------------------------------------------- bilinear 2x upsample
// Matches jax.image.resize bilinear / F.interpolate(align_corners=False).
// in: [B*C, H, W] -> out: [B*C, 2H, 2W].
__global__ void up2_k(const float* __restrict__ in, float* __restrict__ out,
                      int H, int W, long total)
{
    long idx = (long)blockIdx.x * 256 + threadIdx.x;
    if (idx >= total) return;
    const int W2 = 2 * W, H2 = 2 * H;
    int w2 = (int)(idx % W2);
    long t = idx / W2;
    int h2 = (int)(t % H2);
    long bc = t / H2;
    const float* src = in + bc * (size_t)H * W;
    int jx = w2 >> 1, jy = h2 >> 1;
    int x0, y0; float wx0, wy0;
    if (w2 & 1) { x0 = jx;     wx0 = 0.75f; } else { x0 = jx - 1; wx0 = 0.25f; }
    if (h2 & 1) { y0 = jy;     wy0 = 0.75f; } else { y0 = jy - 1; wy0 = 0.25f; }
    int x1 = x0 + 1 > W - 1 ? W - 1 : x0 + 1;
    int y1 = y0 + 1 > H - 1 ? H - 1 : y0 + 1;
    if (x0 < 0) x0 = 0;
    if (y0 < 0) y0 = 0;
    float v00 = src[(size_t)y0 * W + x0], v01 = src[(size_t)y0 * W + x1];
    float v10 = src[(size_t)y1 * W + x0], v11 = src[(size_t)y1 * W + x1];
    float wx1 = 1.f - wx0, wy1 = 1.f - wy0;
    out[idx] = wy0 * (wx0 * v00 + wx1 * v01) + wy1 * (wx0 * v10 + wx1 * v11);
}

// ---------------------------------------------------------------- launcher
extern "C" void kernel_launch(void* const* d_in, const int* in_sizes, int n_in,
                              void* d_out, int out_size, void* d_ws, size_t ws_size,
                              hipStream_t stream)
{
    const float* fea1_l1 = (const float*)d_in[0];
    const float* fea1_l2 = (const float*)d_in[1];
    const float* fea1_l3 = (const float*)d_in[2];
    const float* fea2_l1 = (const float*)d_in[3];
    const float* fea2_l2 = (const float*)d_in[4];
    const float* fea2_l3 = (const float*)d_in[5];
    const float* w128  = (const float*)d_in[6];
    const float* b128  = (const float*)d_in[7];
    const float* w64   = (const float*)d_in[8];
    const float* b64   = (const float*)d_in[9];
    const float* om_w  = (const float*)d_in[10];
    const float* om_b  = (const float*)d_in[11];
    const float* dcn_w = (const float*)d_in[12];
    const float* dcn_b = (const float*)d_in[13];
    float* outp = (float*)d_out;

    float* ws = (float*)d_ws;
    const size_t S1  = (size_t)4 * 64 * 128 * 128;   // 4,194,304
    const size_t S2  = (size_t)4 * 64 * 64 * 64;     // 1,048,576
    const size_t ASZ = (size_t)4 * 216 * 128 * 128;  // 14,155,776
    float* s1  = ws;
    float* s2  = ws + S1;
    float* s3  = ws + 2 * S1;
    float* s4  = ws + 3 * S1;
    float* sA  = ws + 4 * S1;        // offset-mask conv output (216 ch)
    float* sG  = sA + ASZ;           // L2_off  (lives into L1 stage)
    float* sH  = sG + S2;            // L2_fea  (lives into L1 stage)
    float* sWT = sH + S2;            // transposed dcn weights (36864 floats)
    // total: 4*S1 + ASZ + 2*S2 + 36864 = 33,067,008 floats = 132.3 MB <= ws_size

    const dim3 blk(16, 16);
    auto grd = [](int W, int H, int z) { return dim3(W / 16, H / 16, z); };

    const size_t W128C = (size_t)64 * 128 * 9;  // per-conv w128 stride
    const size_t W64C  = (size_t)64 * 64 * 9;
    const size_t OMWC  = (size_t)216 * 64 * 9;

    // ---------------- L3 (32x32) ----------------
    // L3_off_a = lrelu(conv(cat(fea1_l3, fea2_l3), w128[0]))
    conv3x3_k<64,64,64,true><<<grd(32,32,4), blk, 0, stream>>>(
        fea1_l3, fea2_l3, 1.f, w128 + 0*W128C, b128 + 0*64, s1, 32, 32, 64, 1);
    // L3_off = lrelu(conv(L3_off_a, w64[0]))
    conv3x3_k<64,0,64,true><<<grd(32,32,4), blk, 0, stream>>>(
        s1, nullptr, 1.f, w64 + 0*W64C, b64 + 0*64, s2, 32, 32, 64, 1);
    // om3 = conv(L3_off, om_w[0])  (216 ch, 3 chunks of 72)
    conv3x3_k<64,0,72,false><<<grd(32,32,12), blk, 0, stream>>>(
        s2, nullptr, 1.f, om_w + 0*OMWC, om_b + 0*216, sA, 32, 32, 216, 3);
    transpose_dcnw<<<144, 256, 0, stream>>>(dcn_w + 0*W64C, sWT);
    // L3_fea = lrelu(dcn(fea1_l3, om3))
    dcn_k<true><<<grd(32,32,4), blk, 0, stream>>>(fea1_l3, sA, sWT, dcn_b + 0*64, s3, 32, 32);

    // ---------------- L2 (64x64) ----------------
    conv3x3_k<64,64,64,true><<<grd(64,64,4), blk, 0, stream>>>(
        fea1_l2, fea2_l2, 1.f, w128 + 1*W128C, b128 + 1*64, s1, 64, 64, 64, 1);
    // L3_off_up = up2(L3_off)
    up2_k<<<(int)((S2 + 255) / 256), 256, 0, stream>>>(s2, s4, 32, 32, (long)S2);
    // L2_off_b = lrelu(conv(cat(L2_off_a, 2*L3_off_up), w128[2]))
    conv3x3_k<64,64,64,true><<<grd(64,64,4), blk, 0, stream>>>(
        s1, s4, 2.f, w128 + 2*W128C, b128 + 2*64, s2, 64, 64, 64, 1);
    // L2_off = lrelu(conv(L2_off_b, w64[1]))
    conv3x3_k<64,0,64,true><<<grd(64,64,4), blk, 0, stream>>>(
        s2, nullptr, 1.f, w64 + 1*W64C, b64 + 1*64, sG, 64, 64, 64, 1);
    conv3x3_k<64,0,72,false><<<grd(64,64,12), blk, 0, stream>>>(
        sG, nullptr, 1.f, om_w + 1*OMWC, om_b + 1*216, sA, 64, 64, 216, 3);
    transpose_dcnw<<<144, 256, 0, stream>>>(dcn_w + 1*W64C, sWT);
    // L2_fea_raw = dcn(fea1_l2, om2)   (no lrelu)
    dcn_k<false><<<grd(64,64,4), blk, 0, stream>>>(fea1_l2, sA, sWT, dcn_b + 1*64, s1, 64, 64);
    // L3_fea_up = up2(L3_fea)
    up2_k<<<(int)((S2 + 255) / 256), 256, 0, stream>>>(s3, s2, 32, 32, (long)S2);
    // L2_fea = lrelu(conv(cat(L2_fea_raw, L3_fea_up), w128[3]))
    conv3x3_k<64,64,64,true><<<grd(64,64,4), blk, 0, stream>>>(
        s1, s2, 1.f, w128 + 3*W128C, b128 + 3*64, sH, 64, 64, 64, 1);

    // ---------------- L1 (128x128) ----------------
    conv3x3_k<64,64,64,true><<<grd(128,128,4), blk, 0, stream>>>(
        fea1_l1, fea2_l1, 1.f, w128 + 4*W128C, b128 + 4*64, s1, 128, 128, 64, 1);
    // L2_off_up = up2(L2_off)
    up2_k<<<(int)((S1 + 255) / 256), 256, 0, stream>>>(sG, s2, 64, 64, (long)S1);
    conv3x3_k<64,64,64,true><<<grd(128,128,4), blk, 0, stream>>>(
        s1, s2, 2.f, w128 + 5*W128C, b128 + 5*64, s3, 128, 128, 64, 1);
    conv3x3_k<64,0,64,true><<<grd(128,128,4), blk, 0, stream>>>(
        s3, nullptr, 1.f, w64 + 2*W64C, b64 + 2*64, s1, 128, 128, 64, 1);
    conv3x3_k<64,0,72,false><<<grd(128,128,12), blk, 0, stream>>>(
        s1, nullptr, 1.f, om_w + 2*OMWC, om_b + 2*216, sA, 128, 128, 216, 3);
    transpose_dcnw<<<144, 256, 0, stream>>>(dcn_w + 2*W64C, sWT);
    // L1_fea_raw = dcn(fea1_l1, om1)  (no lrelu)
    dcn_k<false><<<grd(128,128,4), blk, 0, stream>>>(fea1_l1, sA, sWT, dcn_b + 2*64, s2, 128, 128);
    // L2_fea_up = up2(L2_fea)
    up2_k<<<(int)((S1 + 255) / 256), 256, 0, stream>>>(sH, s3, 64, 64, (long)S1);
    // L1_fea = conv(cat(L1_fea_raw, L2_fea_up), w128[6])   (NO lrelu)
    conv3x3_k<64,64,64,false><<<grd(128,128,4), blk, 0, stream>>>(
        s2, s3, 1.f, w128 + 6*W128C, b128 + 6*64, s4, 128, 128, 64, 1);

    // ---------------- cascade ----------------
    conv3x3_k<64,64,64,true><<<grd(128,128,4), blk, 0, stream>>>(
        s4, fea2_l1, 1.f, w128 + 7*W128C, b128 + 7*64, s1, 128, 128, 64, 1);
    conv3x3_k<64,0,64,true><<<grd(128,128,4), blk, 0, stream>>>(
        s1, nullptr, 1.f, w64 + 3*W64C, b64 + 3*64, s2, 128, 128, 64, 1);
    conv3x3_k<64,0,72,false><<<grd(128,128,12), blk, 0, stream>>>(
        s2, nullptr, 1.f, om_w + 3*OMWC, om_b + 3*216, sA, 128, 128, 216, 3);
    transpose_dcnw<<<144, 256, 0, stream>>>(dcn_w + 3*W64C, sWT);
    // out = lrelu(dcn(L1_fea, om_cas))
    dcn_k<true><<<grd(128,128,4), blk, 0, stream>>>(s4, sA, sWT, dcn_b + 3*64, outp, 128, 128);
}

// Round 2
// 2939.603 us; speedup vs baseline: 6.7862x; 6.7862x over previous
//
#include <hip/hip_runtime.h>
#include <cstdint>
#include <cstddef>

// PCD Align (EDVR) — fp32, occupancy-oriented restructure.
// B=4, NF=64, DG=8, K=9. Levels: L3 32x32, L2 64x64, L1 128x128.

// -------------------- weight transposes --------------------
// [N][OC][C][9] -> [N][C][9][OC]   (r2 = c*9+k is preserved)
__global__ void transpose_convw(const float* __restrict__ w, float* __restrict__ wt,
                                int OC, int C, long total)
{
    long i = (long)blockIdx.x * 256 + threadIdx.x;
    if (i >= total) return;
    const int per = OC * C * 9;
    int n  = (int)(i / per);
    int r  = (int)(i - (long)n * per);
    int o  = r / (C * 9);
    int r2 = r - o * (C * 9);            // c*9 + k
    wt[(long)n * per + (long)r2 * OC + o] = w[i];
}

// [N][O=64][C=64][9] -> [N][9][64][64]  (k,c,o)
__global__ void transpose_dcnw(const float* __restrict__ w, float* __restrict__ wt, long total)
{
    long i = (long)blockIdx.x * 256 + threadIdx.x;
    if (i >= total) return;
    int n = (int)(i / 36864);
    int r = (int)(i % 36864);
    int o = r / 576;
    int c = (r % 576) / 9;
    int k = r % 9;
    wt[(long)n * 36864 + ((size_t)k * 64 + c) * 64 + o] = w[i];
}

// -------------------- conv 3x3 --------------------
// 8x8 spatial tile, 256 threads = 4 waves. Wave w computes OCPW output
// channels at ocbase = chunk*4*OCPW + w*OCPW. Weights WT laid out [C][9][OCtot]
// so each (c,k) slice is OCPW consecutive floats at a wave-uniform address
// -> s_load_dwordx16. Input may be virtual concat of in1 (C1) and in2 (C2, *scale2).
template<int C1, int C2, int OCPW, bool RELU>
__global__ __launch_bounds__(256)
void conv3x3_k(const float* __restrict__ in1, const float* __restrict__ in2,
               float scale2, const float* __restrict__ WT, const float* __restrict__ bg,
               float* __restrict__ out, int H, int W, int OCtot, int nChunk)
{
    constexpr int C = C1 + C2;
    const int bz = blockIdx.z;
    const int b = bz / nChunk, chunk = bz - b * nChunk;
    const int tid = threadIdx.x;
    const int wid = __builtin_amdgcn_readfirstlane(tid >> 6);   // wave-uniform
    const int p  = tid & 63;
    const int py = p >> 3, px = p & 7;
    const int h0 = blockIdx.y * 8, w0 = blockIdx.x * 8;
    const size_t HW = (size_t)H * W;
    const int ocbase = chunk * (4 * OCPW) + wid * OCPW;

    __shared__ float tile[8][10][11];   // 8 ch x 10x10 halo, +1 col pad

    float acc[OCPW];
#pragma unroll
    for (int o = 0; o < OCPW; ++o) acc[o] = 0.f;

    for (int c0 = 0; c0 < C; c0 += 8) {
        __syncthreads();
        for (int i = tid; i < 800; i += 256) {
            int cc = i / 100, r = i - cc * 100;
            int yy = r / 10, xx = r - yy * 10;
            int gy = h0 + yy - 1, gx = w0 + xx - 1;
            int c = c0 + cc;
            float v = 0.f;
            if (gy >= 0 && gy < H && gx >= 0 && gx < W) {
                if (C2 == 0 || c < C1)
                    v = in1[((size_t)b * C1 + c) * HW + (size_t)gy * W + gx];
                else
                    v = in2[((size_t)b * C2 + (c - C1)) * HW + (size_t)gy * W + gx] * scale2;
            }
            tile[cc][yy][xx] = v;
        }
        __syncthreads();

#pragma unroll
        for (int cc = 0; cc < 8; ++cc) {
            float v[9];
#pragma unroll
            for (int dy = 0; dy < 3; ++dy)
#pragma unroll
                for (int dx = 0; dx < 3; ++dx)
                    v[dy * 3 + dx] = tile[cc][py + dy][px + dx];
            const float* wp = WT + ((size_t)(c0 + cc) * 9) * OCtot + ocbase;
#pragma unroll
            for (int k = 0; k < 9; ++k) {
                const float* wk = wp + (size_t)k * OCtot;   // wave-uniform -> s_load
#pragma unroll
                for (int o = 0; o < OCPW; ++o)
                    acc[o] = fmaf(wk[o], v[k], acc[o]);
            }
        }
    }

    const int h = h0 + py, w = w0 + px;
    float* op = out + ((size_t)b * OCtot + ocbase) * HW + (size_t)h * W + w;
#pragma unroll
    for (int o = 0; o < OCPW; ++o) {
        float r = acc[o] + bg[ocbase + o];
        if (RELU) r = (r >= 0.f) ? r : 0.1f * r;
        op[(size_t)o * HW] = r;
    }
}

// -------------------- DCNv2 --------------------
// 8x8 tile, 4 waves. Wave w samples deformable groups {2w,2w+1}, accumulates
// partial acc[64] over all output channels; LDS reduction at the end.
// Wt: [9][64][64] (k,c,o).
template<bool RELU>
__global__ __launch_bounds__(256)
void dcn_k(const float* __restrict__ x, const float* __restrict__ om,
           const float* __restrict__ Wt, const float* __restrict__ bg,
           float* __restrict__ out, int H, int W)
{
    const int b = blockIdx.z;
    const int tid = threadIdx.x;
    const int wid = __builtin_amdgcn_readfirstlane(tid >> 6);
    const int p = tid & 63;
    const int h = blockIdx.y * 8 + (p >> 3), w = blockIdx.x * 8 + (p & 7);
    const size_t HW = (size_t)H * W;

    float acc[64];
#pragma unroll
    for (int o = 0; o < 64; ++o) acc[o] = 0.f;

    const float* omb = om + (size_t)b * 216 * HW + (size_t)h * W + w;
    const float* xb  = x + (size_t)b * 64 * HW;

    for (int gg = 0; gg < 2; ++gg) {
        const int g = wid * 2 + gg;          // wave-uniform
        for (int k = 0; k < 9; ++k) {
            const int ch = g * 9 + k;
            float oy = omb[(size_t)ch * HW];
            float ox = omb[(size_t)(72 + ch) * HW];
            float mr = omb[(size_t)(144 + ch) * HW];
            float m  = 1.f / (1.f + expf(-mr));

            float pyf = oy + (float)(k / 3 - 1) + (float)h;
            float pxf = ox + (float)(k % 3 - 1) + (float)w;
            float fy = floorf(pyf), fx = floorf(pxf);
            float wy = pyf - fy, wx = pxf - fx;
            int y0 = (int)fy, x0 = (int)fx;
            int y1 = y0 + 1, x1 = x0 + 1;
            bool vy0 = (y0 >= 0) & (y0 < H), vy1 = (y1 >= 0) & (y1 < H);
            bool vx0 = (x0 >= 0) & (x0 < W), vx1 = (x1 >= 0) & (x1 < W);
            int y0c = y0 < 0 ? 0 : (y0 >= H ? H - 1 : y0);
            int y1c = y1 < 0 ? 0 : (y1 >= H ? H - 1 : y1);
            int x0c = x0 < 0 ? 0 : (x0 >= W ? W - 1 : x0);
            int x1c = x1 < 0 ? 0 : (x1 >= W ? W - 1 : x1);
            float w00 = (1.f - wy) * (1.f - wx) * m * ((vy0 & vx0) ? 1.f : 0.f);
            float w01 = (1.f - wy) * wx         * m * ((vy0 & vx1) ? 1.f : 0.f);
            float w10 = wy         * (1.f - wx) * m * ((vy1 & vx0) ? 1.f : 0.f);
            float w11 = wy         * wx         * m * ((vy1 & vx1) ? 1.f : 0.f);
            size_t i00 = (size_t)y0c * W + x0c, i01 = (size_t)y0c * W + x1c;
            size_t i10 = (size_t)y1c * W + x0c, i11 = (size_t)y1c * W + x1c;

            float s[8];
#pragma unroll
            for (int cg = 0; cg < 8; ++cg) {
                const float* xc = xb + (size_t)(g * 8 + cg) * HW;
                s[cg] = w00 * xc[i00] + w01 * xc[i01] + w10 * xc[i10] + w11 * xc[i11];
            }
#pragma unroll
            for (int cg = 0; cg < 8; ++cg) {
                const float* wko = Wt + ((size_t)k * 64 + g * 8 + cg) * 64;  // uniform
                float sv = s[cg];
#pragma unroll
                for (int o = 0; o < 64; ++o)
                    acc[o] = fmaf(wko[o], sv, acc[o]);
            }
        }
    }

    __shared__ float red[3][64][65];    // +1 pad -> conflict-free (stride 65)
    if (wid > 0) {
#pragma unroll
        for (int o = 0; o < 64; ++o) red[wid - 1][p][o] = acc[o];
    }
    __syncthreads();
    if (wid == 0) {
#pragma unroll
        for (int o = 0; o < 64; ++o)
            acc[o] += red[0][p][o] + red[1][p][o] + red[2][p][o];
        float* op = out + ((size_t)b * 64) * HW + (size_t)h * W + w;
#pragma unroll
        for (int o = 0; o < 64; ++o) {
            float r = acc[o] + bg[o];
            if (RELU) r = (r >= 0.f) ? r : 0.1f * r;
            op[(size_t)o * HW] = r;
        }
    }
}

// -------------------- bilinear 2x upsample --------------------
__global__ void up2_k(const float* __restrict__ in, float* __restrict__ out,
                      int H, int W, long total)
{
    long idx = (long)blockIdx.x * 256 + threadIdx.x;
    if (idx >= total) return;
    const int W2 = 2 * W, H2 = 2 * H;
    int w2 = (int)(idx % W2);
    long t = idx / W2;
    int h2 = (int)(t % H2);
    long bc = t / H2;
    const float* src = in + bc * (size_t)H * W;
    int jx = w2 >> 1, jy = h2 >> 1;
    int x0, y0; float wx0, wy0;
    if (w2 & 1) { x0 = jx;     wx0 = 0.75f; } else { x0 = jx - 1; wx0 = 0.25f; }
    if (h2 & 1) { y0 = jy;     wy0 = 0.75f; } else { y0 = jy - 1; wy0 = 0.25f; }
    int x1 = x0 + 1 > W - 1 ? W - 1 : x0 + 1;
    int y1 = y0 + 1 > H - 1 ? H - 1 : y0 + 1;
    if (x0 < 0) x0 = 0;
    if (y0 < 0) y0 = 0;
    float v00 = src[(size_t)y0 * W + x0], v01 = src[(size_t)y0 * W + x1];
    float v10 = src[(size_t)y1 * W + x0], v11 = src[(size_t)y1 * W + x1];
    float wx1 = 1.f - wx0, wy1 = 1.f - wy0;
    out[idx] = wy0 * (wx0 * v00 + wx1 * v01) + wy1 * (wx0 * v10 + wx1 * v11);
}

// -------------------- launcher --------------------
extern "C" void kernel_launch(void* const* d_in, const int* in_sizes, int n_in,
                              void* d_out, int out_size, void* d_ws, size_t ws_size,
                              hipStream_t stream)
{
    const float* fea1_l1 = (const float*)d_in[0];
    const float* fea1_l2 = (const float*)d_in[1];
    const float* fea1_l3 = (const float*)d_in[2];
    const float* fea2_l1 = (const float*)d_in[3];
    const float* fea2_l2 = (const float*)d_in[4];
    const float* fea2_l3 = (const float*)d_in[5];
    const float* w128  = (const float*)d_in[6];
    const float* b128  = (const float*)d_in[7];
    const float* w64   = (const float*)d_in[8];
    const float* b64   = (const float*)d_in[9];
    const float* om_w  = (const float*)d_in[10];
    const float* om_b  = (const float*)d_in[11];
    const float* dcn_w = (const float*)d_in[12];
    const float* dcn_b = (const float*)d_in[13];
    float* outp = (float*)d_out;

    float* ws = (float*)d_ws;
    const size_t S1  = (size_t)4 * 64 * 128 * 128;   // 4,194,304
    const size_t S2  = (size_t)4 * 64 * 64 * 64;     // 1,048,576
    const size_t S3  = (size_t)4 * 64 * 32 * 32;     //   262,144
    const size_t ASZ = (size_t)4 * 216 * 128 * 128;  // 14,155,776
    float* A  = ws;
    float* Bb = ws + S1;
    float* Cb = ws + 2 * S1;
    float* Db = ws + 3 * S1;
    float* sA = ws + 4 * S1;                 // om buffer (216ch, L1-sized)
    float* sG = sA + ASZ - 2 * S2;           // L2_off  (aliases sA tail; om2 uses only 3.54M)
    float* sH = sA + ASZ - S2;               // L2_fea
    float* dT = sA + ASZ;                    // dcn weights transposed, 4*36864
    // total ws: 4*S1 + ASZ + 147456 = 31,080,448 floats = 124.3 MB (< proven 132.3)

    // transposed conv weights live in d_out (only the final dcn writes d_out)
    float* w128T = outp;                     // 8*128*9*64 = 589,824
    float* w64T  = outp + 589824;            // 4*64*9*64  = 147,456
    float* omwT  = outp + 737280;            // 4*64*9*216 = 497,664  (ends 1,234,944 < 4,194,304)

    // small-level aliases
    float* e3a = A;            float* e3b = A + S3;       float* e3c = A + 2 * S3;
    float* f2a = Bb;           float* f2b = Bb + S2;      float* f2c = Bb + 2 * S2;

    const dim3 blk(256);

    // ---- weight transposes ----
    transpose_convw<<<(int)((8l*64*128*9 + 255) / 256), 256, 0, stream>>>(w128, w128T, 64, 128, 8l*64*128*9);
    transpose_convw<<<(int)((4l*64*64*9  + 255) / 256), 256, 0, stream>>>(w64,  w64T,  64, 64,  4l*64*64*9);
    transpose_convw<<<(int)((4l*216*64*9 + 255) / 256), 256, 0, stream>>>(om_w, omwT, 216, 64,  4l*216*64*9);
    transpose_dcnw <<<(int)((4l*36864    + 255) / 256), 256, 0, stream>>>(dcn_w, dT, 4l*36864);

    // ---- L3 (32x32) ----
    conv3x3_k<64,64,16,true ><<<dim3(4,4,4),  blk, 0, stream>>>(fea1_l3, fea2_l3, 1.f, w128T + 0*73728, b128 + 0*64, e3a, 32, 32, 64, 1);
    conv3x3_k<64, 0,16,true ><<<dim3(4,4,4),  blk, 0, stream>>>(e3a, nullptr, 1.f, w64T + 0*36864, b64 + 0*64, e3b, 32, 32, 64, 1);
    conv3x3_k<64, 0,27,false><<<dim3(4,4,8),  blk, 0, stream>>>(e3b, nullptr, 1.f, omwT + 0*124416, om_b + 0*216, sA, 32, 32, 216, 2);
    dcn_k<true ><<<dim3(4,4,4), blk, 0, stream>>>(fea1_l3, sA, dT + 0*36864, dcn_b + 0*64, e3c, 32, 32);

    // ---- L2 (64x64) ----
    conv3x3_k<64,64,16,true ><<<dim3(8,8,4),  blk, 0, stream>>>(fea1_l2, fea2_l2, 1.f, w128T + 1*73728, b128 + 1*64, f2a, 64, 64, 64, 1);
    up2_k<<<(int)((S2 + 255) / 256), 256, 0, stream>>>(e3b, f2b, 32, 32, (long)S2);
    conv3x3_k<64,64,16,true ><<<dim3(8,8,4),  blk, 0, stream>>>(f2a, f2b, 2.f, w128T + 2*73728, b128 + 2*64, f2c, 64, 64, 64, 1);
    conv3x3_k<64, 0,16,true ><<<dim3(8,8,4),  blk, 0, stream>>>(f2c, nullptr, 1.f, w64T + 1*36864, b64 + 1*64, sG, 64, 64, 64, 1);
    conv3x3_k<64, 0,27,false><<<dim3(8,8,8),  blk, 0, stream>>>(sG, nullptr, 1.f, omwT + 1*124416, om_b + 1*216, sA, 64, 64, 216, 2);
    dcn_k<false><<<dim3(8,8,4), blk, 0, stream>>>(fea1_l2, sA, dT + 1*36864, dcn_b + 1*64, f2a, 64, 64);
    up2_k<<<(int)((S2 + 255) / 256), 256, 0, stream>>>(e3c, f2b, 32, 32, (long)S2);
    conv3x3_k<64,64,16,true ><<<dim3(8,8,4),  blk, 0, stream>>>(f2a, f2b, 1.f, w128T + 3*73728, b128 + 3*64, sH, 64, 64, 64, 1);

    // ---- L1 (128x128) ----
    conv3x3_k<64,64,16,true ><<<dim3(16,16,4), blk, 0, stream>>>(fea1_l1, fea2_l1, 1.f, w128T + 4*73728, b128 + 4*64, A, 128, 128, 64, 1);
    up2_k<<<(int)((S1 + 255) / 256), 256, 0, stream>>>(sG, Bb, 64, 64, (long)S1);
    conv3x3_k<64,64,16,true ><<<dim3(16,16,4), blk, 0, stream>>>(A, Bb, 2.f, w128T + 5*73728, b128 + 5*64, Cb, 128, 128, 64, 1);
    conv3x3_k<64, 0,16,true ><<<dim3(16,16,4), blk, 0, stream>>>(Cb, nullptr, 1.f, w64T + 2*36864, b64 + 2*64, A, 128, 128, 64, 1);
    up2_k<<<(int)((S1 + 255) / 256), 256, 0, stream>>>(sH, Bb, 64, 64, (long)S1);
    conv3x3_k<64, 0,27,false><<<dim3(16,16,8), blk, 0, stream>>>(A, nullptr, 1.f, omwT + 2*124416, om_b + 2*216, sA, 128, 128, 216, 2);
    dcn_k<false><<<dim3(16,16,4), blk, 0, stream>>>(fea1_l1, sA, dT + 2*36864, dcn_b + 2*64, Cb, 128, 128);
    conv3x3_k<64,64,16,false><<<dim3(16,16,4), blk, 0, stream>>>(Cb, Bb, 1.f, w128T + 6*73728, b128 + 6*64, Db, 128, 128, 64, 1);

    // ---- cascade ----
    conv3x3_k<64,64,16,true ><<<dim3(16,16,4), blk, 0, stream>>>(Db, fea2_l1, 1.f, w128T + 7*73728, b128 + 7*64, A, 128, 128, 64, 1);
    conv3x3_k<64, 0,16,true ><<<dim3(16,16,4), blk, 0, stream>>>(A, nullptr, 1.f, w64T + 3*36864, b64 + 3*64, Bb, 128, 128, 64, 1);
    conv3x3_k<64, 0,27,false><<<dim3(16,16,8), blk, 0, stream>>>(Bb, nullptr, 1.f, omwT + 3*124416, om_b + 3*216, sA, 128, 128, 216, 2);
    dcn_k<true ><<<dim3(16,16,4), blk, 0, stream>>>(Db, sA, dT + 3*36864, dcn_b + 3*64, outp, 128, 128);
}

// Round 3
// 2438.407 us; speedup vs baseline: 8.1811x; 1.2055x over previous
//
#include <hip/hip_runtime.h>
#include <cstdint>
#include <cstddef>

// PCD Align (EDVR) — convs on MFMA (split-bf16, fp32-accurate), DCN on VALU.
// B=4, NF=64, DG=8, K=9. Levels: L3 32x32, L2 64x64, L1 128x128.

typedef __bf16 bf16x8 __attribute__((ext_vector_type(8)));
typedef float  f32x4  __attribute__((ext_vector_type(4)));

// -------------------- weight split/transpose --------------------
// src [nConv][OC][C][3][3] -> per conv: h[9][OCPAD][C], l[9][OCPAD][C] (bf16)
template<int OCPAD, int C>
__global__ void wsplit_k(const float* __restrict__ src, __bf16* __restrict__ dst,
                         int OC, long total)
{
    const int per = 9 * OCPAD * C;
    long i = (long)blockIdx.x * 256 + threadIdx.x;
    if (i >= total) return;
    int n  = (int)(i / per);
    int r  = (int)(i - (long)n * per);
    int t  = r / (OCPAD * C);
    int r2 = r - t * (OCPAD * C);
    int o  = r2 / C;
    int c  = r2 - o * C;
    float v = (o < OC) ? src[(((long)n * OC + o) * C + c) * 9 + t] : 0.f;
    __bf16 h = (__bf16)v;
    __bf16 l = (__bf16)(v - (float)h);
    __bf16* d = dst + (long)n * 2 * per;
    d[r]       = h;
    d[per + r] = l;
}

// [N][O=64][C=64][9] -> [N][9][64][64]  (k,c,o)  fp32 (for dcn)
__global__ void transpose_dcnw(const float* __restrict__ w, float* __restrict__ wt, long total)
{
    long i = (long)blockIdx.x * 256 + threadIdx.x;
    if (i >= total) return;
    int n = (int)(i / 36864);
    int r = (int)(i % 36864);
    int o = r / 576;
    int c = (r % 576) / 9;
    int k = r % 9;
    wt[(long)n * 36864 + ((size_t)k * 64 + c) * 64 + o] = w[i];
}

// -------------------- conv 3x3 via MFMA 16x16x32 bf16 (split hi/lo) --------------------
// Block: 256 thr = 4 waves, 8x8 spatial tile. Wave w owns 16 pixels (rows 2w,2w+1),
// computes NMT 16-oc M-tiles (all oc of its chunk). X staged per 32-ch chunk in LDS
// as bf16 hi/lo, layout [halo_pix(100)][c(40 padded)]. Weights wt: [9][OCPAD][C] h, then l.
// D = Ah*Bh + Ah*Bl + Al*Bh  (AlBl dropped, ~2^-17 rel).
template<int C1, int C2, int NMT, int OCPAD, bool RELU>
__global__ __launch_bounds__(256)
void conv_mfma_k(const float* __restrict__ in1, const float* __restrict__ in2,
                 float scale2, const __bf16* __restrict__ wt, const float* __restrict__ bg,
                 float* __restrict__ out, int H, int W, int OCtot)
{
    constexpr int C = C1 + C2;
    constexpr int PER = 9 * OCPAD * C;         // h/l block stride
    constexpr int NCHUNK = OCPAD / (NMT * 16);
    const int bz = blockIdx.z;
    const int b = bz / NCHUNK, chunk = bz - b * NCHUNK;
    const int ocblk = chunk * NMT * 16;
    const int tid = threadIdx.x;
    const int wid = __builtin_amdgcn_readfirstlane(tid >> 6);
    const int lane = tid & 63;
    const int pix = lane & 15;                 // B col / D col
    const int oct = lane >> 4;                 // k-octet
    const int h0 = blockIdx.y * 8, w0 = blockIdx.x * 8;
    const size_t HW = (size_t)H * W;

    __shared__ __bf16 XH[100 * 40];
    __shared__ __bf16 XL[100 * 40];

    f32x4 accm[NMT], accc[NMT];
#pragma unroll
    for (int mt = 0; mt < NMT; ++mt) { accm[mt] = f32x4{0,0,0,0}; accc[mt] = f32x4{0,0,0,0}; }

    // per-lane constant pieces
    const int py = 2 * wid + (pix >> 3), px = pix & 7;         // output pixel in tile
    const int pixbase = (py * 10 + px) * 40 + oct * 8;         // LDS elem offset (+tap shift later)
    const int alane = (lane & 15) * C + oct * 8;               // A: oc-row*C + k-octet

    for (int c0 = 0; c0 < C; c0 += 32) {
        __syncthreads();
        // ---- stage 32 channels of 10x10 halo as bf16 h/l, 8 ch per task ----
        for (int task = tid; task < 400; task += 256) {
            int p  = task >> 2, o8 = (task & 3) * 8;
            int y  = p / 10, x = p - y * 10;
            int gy = h0 + y - 1, gx = w0 + x - 1;
            bool valid = (gy >= 0) & (gy < H) & (gx >= 0) & (gx < W);
            int cc = c0 + o8;
            const float* src; float sc;
            if (C2 == 0 || cc < C1) { src = in1 + ((size_t)b * C1 + cc) * HW; sc = 1.f; }
            else                    { src = in2 + ((size_t)b * C2 + (cc - C1)) * HW; sc = scale2; }
            const size_t gofs = (size_t)gy * W + gx;
            bf16x8 hv, lv;
#pragma unroll
            for (int j = 0; j < 8; ++j) {
                float v = valid ? src[(size_t)j * HW + gofs] * sc : 0.f;
                __bf16 h = (__bf16)v;
                hv[j] = h;
                lv[j] = (__bf16)(v - (float)h);
            }
            *(bf16x8*)(&XH[p * 40 + o8]) = hv;
            *(bf16x8*)(&XL[p * 40 + o8]) = lv;
        }
        __syncthreads();

        // ---- 9 taps over this K=32 chunk ----
#pragma unroll
        for (int dy = 0; dy < 3; ++dy) {
#pragma unroll
            for (int dx = 0; dx < 3; ++dx) {
                const int t = dy * 3 + dx;
                const int loff = pixbase + (dy * 10 + dx) * 40;
                bf16x8 bh = *(const bf16x8*)(&XH[loff]);
                bf16x8 bl = *(const bf16x8*)(&XL[loff]);
                const __bf16* wbase = wt + (size_t)(t * OCPAD + ocblk) * C + c0 + alane;
#pragma unroll
                for (int mt = 0; mt < NMT; ++mt) {
                    bf16x8 ah = *(const bf16x8*)(wbase + mt * 16 * C);
                    bf16x8 al = *(const bf16x8*)(wbase + mt * 16 * C + PER);
                    accm[mt] = __builtin_amdgcn_mfma_f32_16x16x32_bf16(ah, bh, accm[mt], 0, 0, 0);
                    accc[mt] = __builtin_amdgcn_mfma_f32_16x16x32_bf16(ah, bl, accc[mt], 0, 0, 0);
                    accc[mt] = __builtin_amdgcn_mfma_f32_16x16x32_bf16(al, bh, accc[mt], 0, 0, 0);
                }
            }
        }
    }

    // ---- store: D row = 4*oct + j (oc), col = pix ----
    const int orow4 = oct * 4;
    float* obase = out + (size_t)b * OCtot * HW + (size_t)(h0 + py) * W + (w0 + px);
#pragma unroll
    for (int mt = 0; mt < NMT; ++mt) {
#pragma unroll
        for (int j = 0; j < 4; ++j) {
            int oc = ocblk + mt * 16 + orow4 + j;
            if (oc < OCtot) {
                float r = accm[mt][j] + accc[mt][j] + bg[oc];
                if (RELU) r = (r >= 0.f) ? r : 0.1f * r;
                obase[(size_t)oc * HW] = r;
            }
        }
    }
}

// -------------------- DCNv2 (unchanged from round 2) --------------------
template<bool RELU>
__global__ __launch_bounds__(256)
void dcn_k(const float* __restrict__ x, const float* __restrict__ om,
           const float* __restrict__ Wt, const float* __restrict__ bg,
           float* __restrict__ out, int H, int W)
{
    const int b = blockIdx.z;
    const int tid = threadIdx.x;
    const int wid = __builtin_amdgcn_readfirstlane(tid >> 6);
    const int p = tid & 63;
    const int h = blockIdx.y * 8 + (p >> 3), w = blockIdx.x * 8 + (p & 7);
    const size_t HW = (size_t)H * W;

    float acc[64];
#pragma unroll
    for (int o = 0; o < 64; ++o) acc[o] = 0.f;

    const float* omb = om + (size_t)b * 216 * HW + (size_t)h * W + w;
    const float* xb  = x + (size_t)b * 64 * HW;

    for (int gg = 0; gg < 2; ++gg) {
        const int g = wid * 2 + gg;
        for (int k = 0; k < 9; ++k) {
            const int ch = g * 9 + k;
            float oy = omb[(size_t)ch * HW];
            float ox = omb[(size_t)(72 + ch) * HW];
            float mr = omb[(size_t)(144 + ch) * HW];
            float m  = 1.f / (1.f + expf(-mr));

            float pyf = oy + (float)(k / 3 - 1) + (float)h;
            float pxf = ox + (float)(k % 3 - 1) + (float)w;
            float fy = floorf(pyf), fx = floorf(pxf);
            float wy = pyf - fy, wx = pxf - fx;
            int y0 = (int)fy, x0 = (int)fx;
            int y1 = y0 + 1, x1 = x0 + 1;
            bool vy0 = (y0 >= 0) & (y0 < H), vy1 = (y1 >= 0) & (y1 < H);
            bool vx0 = (x0 >= 0) & (x0 < W), vx1 = (x1 >= 0) & (x1 < W);
            int y0c = y0 < 0 ? 0 : (y0 >= H ? H - 1 : y0);
            int y1c = y1 < 0 ? 0 : (y1 >= H ? H - 1 : y1);
            int x0c = x0 < 0 ? 0 : (x0 >= W ? W - 1 : x0);
            int x1c = x1 < 0 ? 0 : (x1 >= W ? W - 1 : x1);
            float w00 = (1.f - wy) * (1.f - wx) * m * ((vy0 & vx0) ? 1.f : 0.f);
            float w01 = (1.f - wy) * wx         * m * ((vy0 & vx1) ? 1.f : 0.f);
            float w10 = wy         * (1.f - wx) * m * ((vy1 & vx0) ? 1.f : 0.f);
            float w11 = wy         * wx         * m * ((vy1 & vx1) ? 1.f : 0.f);
            size_t i00 = (size_t)y0c * W + x0c, i01 = (size_t)y0c * W + x1c;
            size_t i10 = (size_t)y1c * W + x0c, i11 = (size_t)y1c * W + x1c;

            float s[8];
#pragma unroll
            for (int cg = 0; cg < 8; ++cg) {
                const float* xc = xb + (size_t)(g * 8 + cg) * HW;
                s[cg] = w00 * xc[i00] + w01 * xc[i01] + w10 * xc[i10] + w11 * xc[i11];
            }
#pragma unroll
            for (int cg = 0; cg < 8; ++cg) {
                const float* wko = Wt + ((size_t)k * 64 + g * 8 + cg) * 64;
                float sv = s[cg];
#pragma unroll
                for (int o = 0; o < 64; ++o)
                    acc[o] = fmaf(wko[o], sv, acc[o]);
            }
        }
    }

    __shared__ float red[3][64][65];
    if (wid > 0) {
#pragma unroll
        for (int o = 0; o < 64; ++o) red[wid - 1][p][o] = acc[o];
    }
    __syncthreads();
    if (wid == 0) {
#pragma unroll
        for (int o = 0; o < 64; ++o)
            acc[o] += red[0][p][o] + red[1][p][o] + red[2][p][o];
        float* op = out + ((size_t)b * 64) * HW + (size_t)h * W + w;
#pragma unroll
        for (int o = 0; o < 64; ++o) {
            float r = acc[o] + bg[o];
            if (RELU) r = (r >= 0.f) ? r : 0.1f * r;
            op[(size_t)o * HW] = r;
        }
    }
}

// -------------------- bilinear 2x upsample --------------------
__global__ void up2_k(const float* __restrict__ in, float* __restrict__ out,
                      int H, int W, long total)
{
    long idx = (long)blockIdx.x * 256 + threadIdx.x;
    if (idx >= total) return;
    const int W2 = 2 * W, H2 = 2 * H;
    int w2 = (int)(idx % W2);
    long t = idx / W2;
    int h2 = (int)(t % H2);
    long bc = t / H2;
    const float* src = in + bc * (size_t)H * W;
    int jx = w2 >> 1, jy = h2 >> 1;
    int x0, y0; float wx0, wy0;
    if (w2 & 1) { x0 = jx;     wx0 = 0.75f; } else { x0 = jx - 1; wx0 = 0.25f; }
    if (h2 & 1) { y0 = jy;     wy0 = 0.75f; } else { y0 = jy - 1; wy0 = 0.25f; }
    int x1 = x0 + 1 > W - 1 ? W - 1 : x0 + 1;
    int y1 = y0 + 1 > H - 1 ? H - 1 : y0 + 1;
    if (x0 < 0) x0 = 0;
    if (y0 < 0) y0 = 0;
    float v00 = src[(size_t)y0 * W + x0], v01 = src[(size_t)y0 * W + x1];
    float v10 = src[(size_t)y1 * W + x0], v11 = src[(size_t)y1 * W + x1];
    float wx1 = 1.f - wx0, wy1 = 1.f - wy0;
    out[idx] = wy0 * (wx0 * v00 + wx1 * v01) + wy1 * (wx0 * v10 + wx1 * v11);
}

// -------------------- launcher --------------------
extern "C" void kernel_launch(void* const* d_in, const int* in_sizes, int n_in,
                              void* d_out, int out_size, void* d_ws, size_t ws_size,
                              hipStream_t stream)
{
    const float* fea1_l1 = (const float*)d_in[0];
    const float* fea1_l2 = (const float*)d_in[1];
    const float* fea1_l3 = (const float*)d_in[2];
    const float* fea2_l1 = (const float*)d_in[3];
    const float* fea2_l2 = (const float*)d_in[4];
    const float* fea2_l3 = (const float*)d_in[5];
    const float* w128  = (const float*)d_in[6];
    const float* b128  = (const float*)d_in[7];
    const float* w64   = (const float*)d_in[8];
    const float* b64   = (const float*)d_in[9];
    const float* om_w  = (const float*)d_in[10];
    const float* om_b  = (const float*)d_in[11];
    const float* dcn_w = (const float*)d_in[12];
    const float* dcn_b = (const float*)d_in[13];
    float* outp = (float*)d_out;

    float* ws = (float*)d_ws;
    const size_t S1  = (size_t)4 * 64 * 128 * 128;   // 4,194,304
    const size_t S2  = (size_t)4 * 64 * 64 * 64;     // 1,048,576
    const size_t S3  = (size_t)4 * 64 * 32 * 32;     //   262,144
    const size_t ASZ = (size_t)4 * 216 * 128 * 128;  // 14,155,776
    float* A  = ws;
    float* Bb = ws + S1;
    float* Cb = ws + 2 * S1;
    float* Db = ws + 3 * S1;
    float* sA = ws + 4 * S1;                 // om buffer (216ch, L1-sized)
    float* sG = sA + ASZ - 2 * S2;           // L2_off (dead before L1 om conv)
    float* sH = sA + ASZ - S2;               // L2_fea (dead before L1 om conv)
    float* dT = sA + ASZ;                    // dcn weights transposed, 4*36864

    // split-bf16 conv weights live in d_out scratch (rewritten every call;
    // final dcn overwrites d_out with the real output afterwards)
    __bf16* U = (__bf16*)d_out;
    __bf16* w128T = U;                        // 8 convs * 2*73728
    __bf16* w64T  = U + 1179648;              // 4 convs * 2*36864
    __bf16* omT   = U + 1474560;              // 4 convs * 2*129024  (ends 2,506,752 bf16 = 5 MB)

    float* e3a = A;   float* e3b = A + S3;   float* e3c = A + 2 * S3;
    float* f2a = Bb;  float* f2b = Bb + S2;  float* f2c = Bb + 2 * S2;

    const dim3 blk(256);

    // ---- weight transforms ----
    {
        long t1 = 8l * 73728;   // w128: OCPAD=64, C=128
        wsplit_k<64,128><<<(int)((t1 + 255) / 256), 256, 0, stream>>>(w128, w128T, 64, t1);
        long t2 = 4l * 36864;   // w64: OCPAD=64, C=64
        wsplit_k<64,64><<<(int)((t2 + 255) / 256), 256, 0, stream>>>(w64, w64T, 64, t2);
        long t3 = 4l * 129024;  // om: OCPAD=224, C=64
        wsplit_k<224,64><<<(int)((t3 + 255) / 256), 256, 0, stream>>>(om_w, omT, 216, t3);
        transpose_dcnw<<<(int)((4l * 36864 + 255) / 256), 256, 0, stream>>>(dcn_w, dT, 4l * 36864);
    }

    // ---- L3 (32x32) ----
    conv_mfma_k<64,64,4,64,true ><<<dim3(4,4,4), blk, 0, stream>>>(fea1_l3, fea2_l3, 1.f, w128T + 0l*147456, b128 + 0*64, e3a, 32, 32, 64);
    conv_mfma_k<64, 0,4,64,true ><<<dim3(4,4,4), blk, 0, stream>>>(e3a, nullptr, 1.f, w64T + 0l*73728, b64 + 0*64, e3b, 32, 32, 64);
    conv_mfma_k<64, 0,7,224,false><<<dim3(4,4,8), blk, 0, stream>>>(e3b, nullptr, 1.f, omT + 0l*258048, om_b + 0*216, sA, 32, 32, 216);
    dcn_k<true ><<<dim3(4,4,4), blk, 0, stream>>>(fea1_l3, sA, dT + 0*36864, dcn_b + 0*64, e3c, 32, 32);

    // ---- L2 (64x64) ----
    conv_mfma_k<64,64,4,64,true ><<<dim3(8,8,4), blk, 0, stream>>>(fea1_l2, fea2_l2, 1.f, w128T + 1l*147456, b128 + 1*64, f2a, 64, 64, 64);
    up2_k<<<(int)((S2 + 255) / 256), 256, 0, stream>>>(e3b, f2b, 32, 32, (long)S2);
    conv_mfma_k<64,64,4,64,true ><<<dim3(8,8,4), blk, 0, stream>>>(f2a, f2b, 2.f, w128T + 2l*147456, b128 + 2*64, f2c, 64, 64, 64);
    conv_mfma_k<64, 0,4,64,true ><<<dim3(8,8,4), blk, 0, stream>>>(f2c, nullptr, 1.f, w64T + 1l*73728, b64 + 1*64, sG, 64, 64, 64);
    conv_mfma_k<64, 0,7,224,false><<<dim3(8,8,8), blk, 0, stream>>>(sG, nullptr, 1.f, omT + 1l*258048, om_b + 1*216, sA, 64, 64, 216);
    dcn_k<false><<<dim3(8,8,4), blk, 0, stream>>>(fea1_l2, sA, dT + 1*36864, dcn_b + 1*64, f2a, 64, 64);
    up2_k<<<(int)((S2 + 255) / 256), 256, 0, stream>>>(e3c, f2b, 32, 32, (long)S2);
    conv_mfma_k<64,64,4,64,true ><<<dim3(8,8,4), blk, 0, stream>>>(f2a, f2b, 1.f, w128T + 3l*147456, b128 + 3*64, sH, 64, 64, 64);

    // ---- L1 (128x128) ----
    conv_mfma_k<64,64,4,64,true ><<<dim3(16,16,4), blk, 0, stream>>>(fea1_l1, fea2_l1, 1.f, w128T + 4l*147456, b128 + 4*64, A, 128, 128, 64);
    up2_k<<<(int)((S1 + 255) / 256), 256, 0, stream>>>(sG, Bb, 64, 64, (long)S1);
    conv_mfma_k<64,64,4,64,true ><<<dim3(16,16,4), blk, 0, stream>>>(A, Bb, 2.f, w128T + 5l*147456, b128 + 5*64, Cb, 128, 128, 64);
    conv_mfma_k<64, 0,4,64,true ><<<dim3(16,16,4), blk, 0, stream>>>(Cb, nullptr, 1.f, w64T + 2l*73728, b64 + 2*64, A, 128, 128, 64);
    up2_k<<<(int)((S1 + 255) / 256), 256, 0, stream>>>(sH, Bb, 64, 64, (long)S1);   // before om conv (sA overlaps sH)
    conv_mfma_k<64, 0,7,224,false><<<dim3(16,16,8), blk, 0, stream>>>(A, nullptr, 1.f, omT + 2l*258048, om_b + 2*216, sA, 128, 128, 216);
    dcn_k<false><<<dim3(16,16,4), blk, 0, stream>>>(fea1_l1, sA, dT + 2*36864, dcn_b + 2*64, Cb, 128, 128);
    conv_mfma_k<64,64,4,64,false><<<dim3(16,16,4), blk, 0, stream>>>(Cb, Bb, 1.f, w128T + 6l*147456, b128 + 6*64, Db, 128, 128, 64);

    // ---- cascade ----
    conv_mfma_k<64,64,4,64,true ><<<dim3(16,16,4), blk, 0, stream>>>(Db, fea2_l1, 1.f, w128T + 7l*147456, b128 + 7*64, A, 128, 128, 64);
    conv_mfma_k<64, 0,4,64,true ><<<dim3(16,16,4), blk, 0, stream>>>(A, nullptr, 1.f, w64T + 3l*73728, b64 + 3*64, Bb, 128, 128, 64);
    conv_mfma_k<64, 0,7,224,false><<<dim3(16,16,8), blk, 0, stream>>>(Bb, nullptr, 1.f, omT + 3l*258048, om_b + 3*216, sA, 128, 128, 216);
    dcn_k<true ><<<dim3(16,16,4), blk, 0, stream>>>(Db, sA, dT + 3*36864, dcn_b + 3*64, outp, 128, 128);
}